// Round 3
// baseline (97.477 us; speedup 1.0000x reference)
//
#include <hip/hip_runtime.h>

// r_t = ALPHA * r_{t-1} + (1-ALPHA) * s_t over T, per (b, h) column.
// Shape: spikes/out = (B=16, T=2048, H=2048) fp32, row-major (h contiguous).
//
// Strategy: split T into 16 chunks of L=128; each chunk warms its state over
// a W=48 read-only halo (0.9^48 * max_r ~ 2.6e-3 << 1.22e-2 threshold),
// making chunks independent -> 512 blocks, 8 waves/CU.
// float4 (dwordx4) loads/stores, unroll-8: 128 B/lane = 8 KB/wave in flight
// (16 MB aggregate) to cover HBM latency. Nontemporal stores: output is
// never re-read, keep it from evicting input lines from L2/L3.

#define ALPHA_F 0.9f
#define OMA_F   0.1f   // (1 - ALPHA)

constexpr int Bdim = 16;
constexpr int Tdim = 2048;
constexpr int Hdim = 2048;

constexpr int CHUNKS  = 16;
constexpr int L       = Tdim / CHUNKS;   // 128 timesteps written per chunk
constexpr int W       = 48;              // warm-up halo
constexpr int THREADS = 256;
constexpr int VEC     = 4;               // floats per thread (float4)
constexpr int HCOV    = THREADS * VEC;   // 1024 h-columns per block
constexpr int UNROLL  = 8;

typedef float v4f __attribute__((ext_vector_type(4)));

__global__ __launch_bounds__(THREADS)
void spike_trace_kernel(const float* __restrict__ spikes,
                        float* __restrict__ out) {
    const int c = blockIdx.x;                       // T-chunk
    const int b = blockIdx.z;                       // batch
    const int h = blockIdx.y * HCOV + threadIdx.x * VEC;

    const int t0 = c * L;                           // first written timestep
    const int tw = (c == 0) ? 0 : (t0 - W);         // warm-up start

    const size_t rowbase = (size_t)b * Tdim * Hdim + (size_t)h;
    const v4f* __restrict__ in4 = (const v4f*)(spikes + rowbase);
    v4f*       __restrict__ ou4 = (v4f*)(out + rowbase);
    const size_t strd = Hdim / VEC;                 // float4 stride per t

    v4f r = {0.0f, 0.0f, 0.0f, 0.0f};

    // ---- warm-up halo: converge state, no stores (empty for chunk 0) ----
    // W=48 = 6 * UNROLL
    for (int t = tw; t < t0; t += UNROLL) {
        v4f s[UNROLL];
#pragma unroll
        for (int u = 0; u < UNROLL; ++u)
            s[u] = in4[(size_t)(t + u) * strd];
#pragma unroll
        for (int u = 0; u < UNROLL; ++u) {
#pragma unroll
            for (int k = 0; k < 4; ++k)
                r[k] = fmaf(ALPHA_F, r[k], OMA_F * s[u][k]);
        }
    }

    // ---- main: update + store L timesteps ----
    for (int t = t0; t < t0 + L; t += UNROLL) {
        v4f s[UNROLL];
#pragma unroll
        for (int u = 0; u < UNROLL; ++u)
            s[u] = in4[(size_t)(t + u) * strd];

        v4f w[UNROLL];
#pragma unroll
        for (int u = 0; u < UNROLL; ++u) {
#pragma unroll
            for (int k = 0; k < 4; ++k) {
                r[k] = fmaf(ALPHA_F, r[k], OMA_F * s[u][k]);
                w[u][k] = r[k];
            }
        }
#pragma unroll
        for (int u = 0; u < UNROLL; ++u)
            __builtin_nontemporal_store(w[u], ou4 + (size_t)(t + u) * strd);
    }
}

extern "C" void kernel_launch(void* const* d_in, const int* in_sizes, int n_in,
                              void* d_out, int out_size, void* d_ws, size_t ws_size,
                              hipStream_t stream) {
    const float* spikes = (const float*)d_in[0];
    float* out = (float*)d_out;

    dim3 grid(CHUNKS, Hdim / HCOV, Bdim);   // 16 x 2 x 16 = 512 blocks
    dim3 block(THREADS);
    spike_trace_kernel<<<grid, block, 0, stream>>>(spikes, out);
}

// Round 4
// 89.419 us; speedup vs baseline: 1.0901x; 1.0901x over previous
//
#include <hip/hip_runtime.h>

// r_t = ALPHA * r_{t-1} + (1-ALPHA) * s_t over T, per (b, h) column.
// Shape: spikes/out = (B=16, T=2048, H=2048) fp32, row-major (h contiguous).
//
// Strategy: split T into 8 chunks of L=256; each chunk warms its state over
// a W=64 read-only halo (0.9^65 ~ 1.1e-3 << 1.22e-2 threshold), making
// chunks independent -> 512 blocks, 8 waves/CU.
//
// Grid order: chunk index is the SLOWEST dim with linear stride 64 (multiple
// of 8 XCDs), so all T-chunks of one (h-group, b) column land on the same
// XCD -> halo re-reads hit that XCD's L2/L3 instead of HBM.
//
// UNROLL=16 float2 loads: 8 KB/wave in flight (16 MB aggregate) covers HBM
// latency. Nontemporal stores: output is never re-read; keep it from
// evicting input lines from L2/L3.

#define ALPHA_F 0.9f
#define OMA_F   0.1f   // (1 - ALPHA)

constexpr int Bdim = 16;
constexpr int Tdim = 2048;
constexpr int Hdim = 2048;

constexpr int CHUNKS  = 8;
constexpr int L       = Tdim / CHUNKS;   // 256 timesteps written per chunk
constexpr int W       = 64;              // warm-up halo (0.9^65 ~ 1.1e-3)
constexpr int THREADS = 256;
constexpr int VEC     = 2;               // floats per thread (float2 loads)
constexpr int HCOV    = THREADS * VEC;   // 512 h-columns per block
constexpr int HGROUPS = Hdim / HCOV;     // 4
constexpr int UNROLL  = 16;              // W and L divisible by UNROLL

typedef float v2f __attribute__((ext_vector_type(2)));

__global__ __launch_bounds__(THREADS)
void spike_trace_kernel(const float* __restrict__ spikes,
                        float* __restrict__ out) {
    // grid = (HGROUPS, Bdim, CHUNKS): linear stride of chunk = 64 (== 0 mod
    // 8 XCDs) -> same (hg, b) column's chunks share an XCD.
    const int hg = blockIdx.x;
    const int b  = blockIdx.y;
    const int c  = blockIdx.z;

    const int h  = hg * HCOV + threadIdx.x * VEC;
    const int t0 = c * L;                           // first written timestep
    const int tw = (c == 0) ? 0 : (t0 - W);         // warm-up start

    const size_t rowbase = (size_t)b * Tdim * Hdim + (size_t)h;
    const v2f* __restrict__ in2 = (const v2f*)(spikes + rowbase);
    v2f*       __restrict__ ou2 = (v2f*)(out + rowbase);
    const size_t strd = Hdim / VEC;                 // float2 stride per t

    float r0 = 0.0f, r1 = 0.0f;

    // ---- warm-up halo: converge state, no stores (empty for chunk 0) ----
    for (int t = tw; t < t0; t += UNROLL) {
        v2f s[UNROLL];
#pragma unroll
        for (int u = 0; u < UNROLL; ++u)
            s[u] = in2[(size_t)(t + u) * strd];
#pragma unroll
        for (int u = 0; u < UNROLL; ++u) {
            r0 = fmaf(ALPHA_F, r0, OMA_F * s[u].x);
            r1 = fmaf(ALPHA_F, r1, OMA_F * s[u].y);
        }
    }

    // ---- main: update + store L timesteps ----
    for (int t = t0; t < t0 + L; t += UNROLL) {
        v2f s[UNROLL];
#pragma unroll
        for (int u = 0; u < UNROLL; ++u)
            s[u] = in2[(size_t)(t + u) * strd];

        v2f w[UNROLL];
#pragma unroll
        for (int u = 0; u < UNROLL; ++u) {
            r0 = fmaf(ALPHA_F, r0, OMA_F * s[u].x);
            r1 = fmaf(ALPHA_F, r1, OMA_F * s[u].y);
            w[u].x = r0;
            w[u].y = r1;
        }
#pragma unroll
        for (int u = 0; u < UNROLL; ++u)
            __builtin_nontemporal_store(w[u], ou2 + (size_t)(t + u) * strd);
    }
}

extern "C" void kernel_launch(void* const* d_in, const int* in_sizes, int n_in,
                              void* d_out, int out_size, void* d_ws, size_t ws_size,
                              hipStream_t stream) {
    const float* spikes = (const float*)d_in[0];
    float* out = (float*)d_out;

    dim3 grid(HGROUPS, Bdim, CHUNKS);   // 4 x 16 x 8 = 512 blocks
    dim3 block(THREADS);
    spike_trace_kernel<<<grid, block, 0, stream>>>(spikes, out);
}

// Round 5
// 84.542 us; speedup vs baseline: 1.1530x; 1.0577x over previous
//
#include <hip/hip_runtime.h>

// r_t = ALPHA * r_{t-1} + (1-ALPHA) * s_t over T, per (b, h) column.
// Shape: spikes/out = (B=16, T=2048, H=2048) fp32, row-major (h contiguous).
//
// Strategy: split T into 4 chunks of L=512; each chunk warms its state over
// a W=64 read-only halo (0.9^65 ~ 1.1e-3 << 1.22e-2 threshold), making
// chunks independent. VEC=1 (scalar dword per thread) keeps 2048 waves
// (8 waves/CU) despite fewer chunks; halo traffic halves vs CHUNKS=8
// (3x64 rows = 25 MB vs 58.7 MB). Rate model: 6.65 TB/s effective demand
// rate (measured R2/R4) -> 561 MB / 6.65 ~ 84 us.
//
// Chunk is the slowest grid dim (stride 128 == 0 mod 8 XCDs): same-column
// chunks land on the same XCD, so halo re-reads hit that XCD's L2.
// Nontemporal stores: output is never re-read.

#define ALPHA_F 0.9f
#define OMA_F   0.1f   // (1 - ALPHA)

constexpr int Bdim = 16;
constexpr int Tdim = 2048;
constexpr int Hdim = 2048;

constexpr int CHUNKS  = 4;
constexpr int L       = Tdim / CHUNKS;   // 512 timesteps written per chunk
constexpr int W       = 64;              // warm-up halo (0.9^65 ~ 1.1e-3)
constexpr int THREADS = 256;
constexpr int VEC     = 1;               // one h-column per thread
constexpr int HCOV    = THREADS * VEC;   // 256 h-columns per block
constexpr int HGROUPS = Hdim / HCOV;     // 8
constexpr int UNROLL  = 16;              // W and L divisible by UNROLL

__global__ __launch_bounds__(THREADS)
void spike_trace_kernel(const float* __restrict__ spikes,
                        float* __restrict__ out) {
    // grid = (HGROUPS, Bdim, CHUNKS)
    const int hg = blockIdx.x;
    const int b  = blockIdx.y;
    const int c  = blockIdx.z;

    const int h  = hg * HCOV + threadIdx.x;
    const int t0 = c * L;                           // first written timestep
    const int tw = (c == 0) ? 0 : (t0 - W);         // warm-up start

    const size_t rowbase = (size_t)b * Tdim * Hdim + (size_t)h;
    const float* __restrict__ in1 = spikes + rowbase;
    float*       __restrict__ ou1 = out + rowbase;
    const size_t strd = Hdim;                       // float stride per t

    float r = 0.0f;

    // ---- warm-up halo: converge state, no stores (empty for chunk 0) ----
    for (int t = tw; t < t0; t += UNROLL) {
        float s[UNROLL];
#pragma unroll
        for (int u = 0; u < UNROLL; ++u)
            s[u] = in1[(size_t)(t + u) * strd];
#pragma unroll
        for (int u = 0; u < UNROLL; ++u)
            r = fmaf(ALPHA_F, r, OMA_F * s[u]);
    }

    // ---- main: update + store L timesteps ----
    for (int t = t0; t < t0 + L; t += UNROLL) {
        float s[UNROLL];
#pragma unroll
        for (int u = 0; u < UNROLL; ++u)
            s[u] = in1[(size_t)(t + u) * strd];

        float w[UNROLL];
#pragma unroll
        for (int u = 0; u < UNROLL; ++u) {
            r = fmaf(ALPHA_F, r, OMA_F * s[u]);
            w[u] = r;
        }
#pragma unroll
        for (int u = 0; u < UNROLL; ++u)
            __builtin_nontemporal_store(w[u], ou1 + (size_t)(t + u) * strd);
    }
}

extern "C" void kernel_launch(void* const* d_in, const int* in_sizes, int n_in,
                              void* d_out, int out_size, void* d_ws, size_t ws_size,
                              hipStream_t stream) {
    const float* spikes = (const float*)d_in[0];
    float* out = (float*)d_out;

    dim3 grid(HGROUPS, Bdim, CHUNKS);   // 8 x 16 x 4 = 512 blocks
    dim3 block(THREADS);
    spike_trace_kernel<<<grid, block, 0, stream>>>(spikes, out);
}

// Round 6
// 84.047 us; speedup vs baseline: 1.1598x; 1.0059x over previous
//
#include <hip/hip_runtime.h>

// r_t = ALPHA * r_{t-1} + (1-ALPHA) * s_t over T, per (b, h) column.
// Shape: spikes/out = (B=16, T=2048, H=2048) fp32, row-major (h contiguous).
//
// Strategy: split T into 2 chunks of L=1024; chunk 1 warms its state over a
// W=64 read-only halo (0.9^65 ~ 1.1e-3 << 1.22e-2 threshold). Demand bytes
// = 2x268.4 + 8.4 MB halo = 545 MB; at the measured 6.65 TB/s demand rate
// (R2/R4/R5) -> ~82 us.
//
// Occupancy: 2048 cols x 16 b x 2 chunks / 256 thr = 256 blocks = 1024
// waves (1/SIMD). Compensate with UNROLL=32: 8 KB/wave in flight -> 8 MB
// aggregate, matching the configuration that sustained 6.65 TB/s.
//
// Chunk is the slowest grid dim (stride 128 == 0 mod 8 XCDs). Nontemporal
// stores: output is never re-read.

#define ALPHA_F 0.9f
#define OMA_F   0.1f   // (1 - ALPHA)

constexpr int Bdim = 16;
constexpr int Tdim = 2048;
constexpr int Hdim = 2048;

constexpr int CHUNKS  = 2;
constexpr int L       = Tdim / CHUNKS;   // 1024 timesteps written per chunk
constexpr int W       = 64;              // warm-up halo (0.9^65 ~ 1.1e-3)
constexpr int THREADS = 256;
constexpr int VEC     = 1;               // one h-column per thread
constexpr int HCOV    = THREADS * VEC;   // 256 h-columns per block
constexpr int HGROUPS = Hdim / HCOV;     // 8
constexpr int UNROLL  = 32;              // W and L divisible by UNROLL

__global__ __launch_bounds__(THREADS)
void spike_trace_kernel(const float* __restrict__ spikes,
                        float* __restrict__ out) {
    // grid = (HGROUPS, Bdim, CHUNKS)
    const int hg = blockIdx.x;
    const int b  = blockIdx.y;
    const int c  = blockIdx.z;

    const int h  = hg * HCOV + threadIdx.x;
    const int t0 = c * L;                           // first written timestep
    const int tw = (c == 0) ? 0 : (t0 - W);         // warm-up start

    const size_t rowbase = (size_t)b * Tdim * Hdim + (size_t)h;
    const float* __restrict__ in1 = spikes + rowbase;
    float*       __restrict__ ou1 = out + rowbase;
    const size_t strd = Hdim;                       // float stride per t

    float r = 0.0f;

    // ---- warm-up halo: converge state, no stores (empty for chunk 0) ----
    for (int t = tw; t < t0; t += UNROLL) {
        float s[UNROLL];
#pragma unroll
        for (int u = 0; u < UNROLL; ++u)
            s[u] = in1[(size_t)(t + u) * strd];
#pragma unroll
        for (int u = 0; u < UNROLL; ++u)
            r = fmaf(ALPHA_F, r, OMA_F * s[u]);
    }

    // ---- main: update + store L timesteps ----
    for (int t = t0; t < t0 + L; t += UNROLL) {
        float s[UNROLL];
#pragma unroll
        for (int u = 0; u < UNROLL; ++u)
            s[u] = in1[(size_t)(t + u) * strd];

        float w[UNROLL];
#pragma unroll
        for (int u = 0; u < UNROLL; ++u) {
            r = fmaf(ALPHA_F, r, OMA_F * s[u]);
            w[u] = r;
        }
#pragma unroll
        for (int u = 0; u < UNROLL; ++u)
            __builtin_nontemporal_store(w[u], ou1 + (size_t)(t + u) * strd);
    }
}

extern "C" void kernel_launch(void* const* d_in, const int* in_sizes, int n_in,
                              void* d_out, int out_size, void* d_ws, size_t ws_size,
                              hipStream_t stream) {
    const float* spikes = (const float*)d_in[0];
    float* out = (float*)d_out;

    dim3 grid(HGROUPS, Bdim, CHUNKS);   // 8 x 16 x 2 = 256 blocks
    dim3 block(THREADS);
    spike_trace_kernel<<<grid, block, 0, stream>>>(spikes, out);
}